// Round 10
// baseline (153.305 us; speedup 1.0000x reference)
//
#include <hip/hip_runtime.h>
#include <stdint.h>

#define B_ 32
#define P_ 8732
#define PPAD 8736      // P_ rounded up to x4 for uint4 key loads
#define C_ 21
#define TOPK 200
#define TGT 228        // center of acceptable count window [200,256]
#define CONF_T 0.01f
#define NMS_T 0.45f
#define NCH2 35        // ceil(P_/256)
#define NT 640         // 10 waves: 3 blocks/CU cap == ceil(672/256) -> all resident, 26 waves/CU
#define KV4 4          // ceil((PPAD/4)/NT)

__device__ __forceinline__ uint32_t f2s(float f) {
    uint32_t u = __float_as_uint(f);
    return (u & 0x80000000u) ? ~u : (u | 0x80000000u);
}
__device__ __forceinline__ float s2f(uint32_t s) {
    uint32_t b = (s & 0x80000000u) ? (s & 0x7FFFFFFFu) : ~s;
    return __uint_as_float(b);
}
__device__ __forceinline__ uint32_t keyof(float v) {
    return f2s((v > CONF_T) ? v : -1.0f);
}

// conf (B,P,C) f32 -> (B,C,PPAD) sortable-u32 keys, threshold applied, pads=0.
// float4 tile loads; uint4 key stores (thread = 4-prior group x class-slice).
__global__ __launch_bounds__(256) void transpose_keys(const float* __restrict__ conf,
                                                      uint32_t* __restrict__ keys) {
    const int b = blockIdx.x / NCH2;
    const int ch = blockIdx.x % NCH2;
    const int p0 = ch * 256;
    const int n = min(256, P_ - p0);          // 256 or 28; always %4 == 0
    const int tid = threadIdx.x;
    __shared__ float tile[256 * C_];
    const float4* src4 = (const float4*)(conf + ((size_t)b * P_ + p0) * C_);
    float4* tile4 = (float4*)tile;
    const int tot4 = (n * C_) >> 2;
    for (int i = tid; i < tot4; i += 256) tile4[i] = src4[i];
    __syncthreads();
    uint32_t* dst = keys + (size_t)b * C_ * PPAD + p0;
    const int pg = tid & 63;                  // 4-prior group
    const int cs = tid >> 6;                  // class slice 0..3
    const int ng = n >> 2;                    // 64 or 7
    if (pg < ng) {
        for (int c = cs; c < C_; c += 4) {
            const float* tp = &tile[4 * pg * C_ + c];
            uint4 k;
            k.x = keyof(tp[0 * C_]);
            k.y = keyof(tp[1 * C_]);
            k.z = keyof(tp[2 * C_]);
            k.w = keyof(tp[3 * C_]);
            *(uint4*)(dst + (size_t)c * PPAD + 4 * pg) = k;
        }
    }
    if (ch == NCH2 - 1 && pg == ng) {         // single pad group (PPAD-P_ == 4)
        for (int c = cs; c < C_; c += 4)
            *(uint4*)(dst + (size_t)c * PPAD + 4 * pg) = make_uint4(0u, 0u, 0u, 0u);
    }
}

template<bool RAW>
__global__ __launch_bounds__(NT, 7) void detect_kernel(
    const float* __restrict__ loc, const float* __restrict__ prior,
    const uint32_t* __restrict__ keys, const float* __restrict__ conf,
    float* __restrict__ out)
{
    const int task = blockIdx.x;
    const int b = task / C_;
    const int c = task % C_;
    const int tid = threadIdx.x;
    const int lane = tid & 63;
    float* outp = out + (size_t)task * TOPK * 5;

    if (c == 0) {  // out.at[:,0].set(0.0)
        for (int e = tid; e < TOPK * 5; e += NT) outp[e] = 0.0f;
        return;
    }

    __shared__ uint64_t cand[256];
    __shared__ float4 bbox[TOPK];
    __shared__ float bar[TOPK], bs[TOPK];
    __shared__ unsigned long long msk[TOPK * 4];
    __shared__ unsigned long long vmask[4];
    __shared__ int order[TOPK];
    __shared__ int s_cnt, s_nk;
    __shared__ int s_c2[2];

    // ---- load this task's 8736 keys into registers as uint4 (pads = 0) ----
    uint4 kv[KV4];
    if (!RAW) {
        const uint4* kp = (const uint4*)(keys + (size_t)task * PPAD);
        #pragma unroll
        for (int r = 0; r < KV4; ++r) {
            int q = tid + r * NT;
            kv[r] = (q < PPAD / 4) ? kp[q] : make_uint4(0u, 0u, 0u, 0u);
        }
    } else {
        const float* sp = conf + (size_t)b * P_ * C_ + c;
        #pragma unroll
        for (int r = 0; r < KV4; ++r) {
            uint32_t uu[4];
            #pragma unroll
            for (int c4 = 0; c4 < 4; ++c4) {
                int p = (tid + r * NT) * 4 + c4;
                if (p < P_) {
                    float v = sp[(size_t)p * C_];
                    v = (v > CONF_T) ? v : -1.0f;
                    uu[c4] = f2s(v);
                } else uu[c4] = 0u;
            }
            kv[r] = make_uint4(uu[0], uu[1], uu[2], uu[3]);
        }
    }

    // ---- one-time zeroing (hidden under the in-flight global key loads) ----
    if (tid == 0) s_cnt = 0;
    if (tid < 2) s_c2[tid] = 0;
    for (int i2 = tid; i2 < TOPK * 4; i2 += NT) msk[i2] = 0ull;
    __syncthreads();

    // ---- top-200 threshold via interpolated count-search (conf ~ uniform:
    //      first probe lands count in [200,256] ~94% of the time; regula-falsi
    //      step + bisection fallback guarantees progress) ----
    uint32_t lo = 0u, hi = 0xFFFFFFFFu;
    uint32_t t = f2s(1.0f - (float)TGT / (float)P_);
    uint32_t vthr = 0u;
    for (int it = 0; ; ++it) {
        const int slot = it & 1;
        int my = 0;
        #pragma unroll
        for (int r = 0; r < KV4; ++r)
            my += (kv[r].x >= t) + (kv[r].y >= t) + (kv[r].z >= t) + (kv[r].w >= t);
        #pragma unroll
        for (int d = 1; d < 64; d <<= 1) my += __shfl_down(my, d);
        if (lane == 0) atomicAdd(&s_c2[slot], my);
        __syncthreads();
        const int cnt = s_c2[slot];              // uniform across block
        __syncthreads();
        if (tid == 0) s_c2[slot] = 0;            // reused at it+2; it+1's barriers order this
        if (cnt >= TOPK && cnt <= 256) { vthr = t; break; }
        if (cnt > 256) lo = t; else hi = t;
        if (hi - lo <= 1) { vthr = lo; break; }  // tie collapse: measure-zero on f32 uniforms
        uint32_t tn = 0;
        bool bis = (it >= 8) || (cnt == 0);
        if (!bis) {
            const float sc = s2f(t);
            const float sn = 1.0f - (1.0f - sc) * (float)TGT / (float)cnt;
            tn = f2s(sn);
            if (!(tn > lo && tn < hi)) bis = true;
        }
        if (bis) tn = lo + ((hi - lo) >> 1);
        t = tn;
    }

    // ---- compact candidates >= vthr ----
    #pragma unroll
    for (int r = 0; r < KV4; ++r) {
        const int pb = (tid + r * NT) * 4;
        uint32_t uu[4] = {kv[r].x, kv[r].y, kv[r].z, kv[r].w};
        #pragma unroll
        for (int c4 = 0; c4 < 4; ++c4) {
            uint32_t u = uu[c4];
            if (u >= vthr) {
                int pos = atomicAdd(&s_cnt, 1);
                if (pos < 256) cand[pos] = ((uint64_t)u << 32) | (uint32_t)(~(uint32_t)(pb + c4));
            }
        }
    }
    __syncthreads();
    if (tid < 256 && tid >= s_cnt) cand[tid] = 0ull;   // pad sorts to the end
    __syncthreads();

    // ---- bitonic sort 256 keys desc (val desc, idx asc) == jax.lax.top_k ----
    uint64_t v = (tid < 256) ? cand[tid] : 0ull;
    for (int kk = 2; kk <= 256; kk <<= 1) {
        for (int j = kk >> 1; j > 0; j >>= 1) {
            if (j >= 64) {
                __syncthreads();
                if (tid < 256) cand[tid] = v;
                __syncthreads();
                if (tid < 256) {
                    uint64_t pv = cand[tid ^ j];
                    bool keepmax = (((tid & j) == 0) == ((tid & kk) == 0));
                    v = keepmax ? (v > pv ? v : pv) : (v < pv ? v : pv);
                }
            } else if (tid < 256) {
                uint64_t pv = __shfl_xor(v, j);
                bool keepmax = (((tid & j) == 0) == ((tid & kk) == 0));
                v = keepmax ? (v > pv ? v : pv) : (v < pv ? v : pv);
            }
        }
    }

    // ---- decode top-200 boxes (exact ref f32 op order, no contraction) ----
    float my_sc = -1.0f;
    if (tid < TOPK) {
        uint32_t su = (uint32_t)(v >> 32);
        int p = (int)(~(uint32_t)v);
        my_sc = s2f(su);
        const float4 l4 = *(const float4*)(loc + ((size_t)b * P_ + p) * 4);
        const float4 pr = *(const float4*)(prior + (size_t)p * 4);
        float cx = __fadd_rn(pr.x, __fmul_rn(__fmul_rn(l4.x, 0.1f), pr.z));
        float cy = __fadd_rn(pr.y, __fmul_rn(__fmul_rn(l4.y, 0.1f), pr.w));
        float ew = (float)exp((double)__fmul_rn(l4.z, 0.2f));
        float eh = (float)exp((double)__fmul_rn(l4.w, 0.2f));
        float w  = __fmul_rn(pr.z, ew);
        float h  = __fmul_rn(pr.w, eh);
        float x1 = __fsub_rn(cx, __fmul_rn(w, 0.5f));
        float y1 = __fsub_rn(cy, __fmul_rn(h, 0.5f));
        float x2 = __fadd_rn(x1, w);
        float y2 = __fadd_rn(y1, h);
        bs[tid] = my_sc;
        bbox[tid] = make_float4(x1, y1, x2, y2);
        bar[tid] = __fmul_rn(__fsub_rn(x2, x1), __fsub_rn(y2, y1));
    }
    {
        unsigned long long bm = __ballot(tid < TOPK && my_sc > CONF_T);
        if (lane == 0 && tid < 256) vmask[tid >> 6] = bm;
    }
    __syncthreads();

    // ---- pairwise IoU: balanced row-pairing (6 sub-lanes), div tie-band screened ----
    if (tid < 600) {
        const int rp = tid / 6;        // row-pair id in [0,100)
        const int s  = tid - rp * 6;   // sub-lane in [0,6)
        #pragma unroll
        for (int pass = 0; pass < 2; ++pass) {
            const int j  = pass ? (199 - rp) : rp;
            const int i0 = j + 1 + s;
            const float4 bj = bbox[j];
            const float  aj = bar[j];
            for (int i = i0; i < TOPK; i += 6) {
                const float4 bi = bbox[i];
                float xx1 = fmaxf(bj.x, bi.x);
                float yy1 = fmaxf(bj.y, bi.y);
                float xx2 = fminf(bj.z, bi.z);
                float yy2 = fminf(bj.w, bi.w);
                float dx = fmaxf(__fsub_rn(xx2, xx1), 0.0f);
                float dy = fmaxf(__fsub_rn(yy2, yy1), 0.0f);
                float inter = __fmul_rn(dx, dy);
                if (inter > 0.0f) {
                    float uni = __fsub_rn(__fadd_rn(aj, bar[i]), inter);
                    float t45 = __fmul_rn(NMS_T, uni);
                    float mar = __fmul_rn(t45, 1e-6f);
                    bool sup;
                    if (inter > __fadd_rn(t45, mar)) sup = true;
                    else if (inter < __fsub_rn(t45, mar)) sup = false;
                    else sup = (inter / uni > NMS_T);   // exact IEEE path, tie band only
                    if (sup) atomicOr(&msk[j * 4 + (i >> 6)], 1ull << (i & 63));
                }
            }
        }
    }
    __syncthreads();

    // ---- greedy NMS: word-blocked wave-0 scan (1 shfl/pick, deferred cross-word OR) ----
    if (tid < 64) {
        const int L = tid;
        auto or_reduce = [&](unsigned long long x) {
            #pragma unroll
            for (int d = 1; d < 64; d <<= 1) x |= __shfl_xor(x, d);
            return x;
        };
        unsigned long long s1 = 0, s2 = 0, s3 = 0;   // incoming suppression, words 1..3
        int nk = 0;
        #pragma unroll
        for (int w = 0; w < 4; ++w) {
            const int j = (w << 6) | L;
            unsigned long long r0 = 0, r1 = 0, r2 = 0, r3 = 0;
            if (j < TOPK) {
                const unsigned long long* mr = &msk[j * 4];
                r0 = mr[0]; r1 = mr[1]; r2 = mr[2]; r3 = mr[3];
            }
            const unsigned long long rself = (w == 0) ? r0 : (w == 1) ? r1
                                           : (w == 2) ? r2 : r3;
            unsigned long long sw = (w == 0) ? 0ull : (w == 1) ? s1
                                  : (w == 2) ? s2 : s3;
            unsigned long long alive = vmask[w] & ~sw;
            unsigned long long pm = 0;
            while (alive) {
                int jl = __ffsll(alive) - 1;
                if (L == 0) order[nk] = (w << 6) | jl;
                ++nk;
                sw |= __shfl(rself, jl);             // suppression within this word
                pm |= (1ull << jl);
                alive &= ~(sw | (1ull << jl));
            }
            if (pm) {   // deferred: OR picked rows' later-word masks (mask bits are i>j only)
                const bool picked = (pm >> L) & 1ull;
                if (w == 0) {
                    s1 |= or_reduce(picked ? r1 : 0ull);
                    s2 |= or_reduce(picked ? r2 : 0ull);
                    s3 |= or_reduce(picked ? r3 : 0ull);
                } else if (w == 1) {
                    s2 |= or_reduce(picked ? r2 : 0ull);
                    s3 |= or_reduce(picked ? r3 : 0ull);
                } else if (w == 2) {
                    s3 |= or_reduce(picked ? r3 : 0ull);
                }
            }
        }
        if (L == 0) s_nk = nk;
    }
    __syncthreads();

    // ---- compacted output ----
    const int nk = s_nk;
    for (int e = tid; e < TOPK * 5; e += NT) {
        int r = e / 5;
        int f = e - r * 5;
        float val = 0.0f;
        if (r < nk) {
            int j = order[r];
            float4 bb = bbox[j];
            val = (f == 0) ? bs[j] : (f == 1) ? bb.x : (f == 2) ? bb.y
                : (f == 3) ? bb.z : bb.w;
        }
        outp[e] = val;
    }
}

extern "C" void kernel_launch(void* const* d_in, const int* in_sizes, int n_in,
                              void* d_out, int out_size, void* d_ws, size_t ws_size,
                              hipStream_t stream) {
    const float* loc   = (const float*)d_in[0];
    const float* conf  = (const float*)d_in[1];
    const float* prior = (const float*)d_in[2];
    float* out = (float*)d_out;

    const size_t need = (size_t)B_ * C_ * PPAD * sizeof(uint32_t);
    if (ws_size >= need) {
        uint32_t* keys = (uint32_t*)d_ws;
        transpose_keys<<<B_ * NCH2, 256, 0, stream>>>(conf, keys);
        detect_kernel<false><<<B_ * C_, NT, 0, stream>>>(loc, prior, keys, conf, out);
    } else {
        detect_kernel<true><<<B_ * C_, NT, 0, stream>>>(loc, prior, nullptr, conf, out);
    }
}

// Round 11
// 124.397 us; speedup vs baseline: 1.2324x; 1.2324x over previous
//
#include <hip/hip_runtime.h>
#include <stdint.h>

#define B_ 32
#define P_ 8732
#define PPAD 8736      // P_ rounded up to x4 for uint4 key loads
#define C_ 21
#define TOPK 200
#define TGT 228        // center of acceptable count window [200,256]
#define CONF_T 0.01f
#define NMS_T 0.45f
#define NCH2 35        // ceil(P_/256)
#define NT 512         // 8-wave blocks: the only shape that packs (R5/R7/R10 evidence)
#define KV4 5          // ceil((PPAD/4)/NT)

__device__ __forceinline__ uint32_t f2s(float f) {
    uint32_t u = __float_as_uint(f);
    return (u & 0x80000000u) ? ~u : (u | 0x80000000u);
}
__device__ __forceinline__ float s2f(uint32_t s) {
    uint32_t b = (s & 0x80000000u) ? (s & 0x7FFFFFFFu) : ~s;
    return __uint_as_float(b);
}
__device__ __forceinline__ uint32_t keyof(float v) {
    return f2s((v > CONF_T) ? v : -1.0f);
}

// conf (B,P,C) f32 -> (B,C,PPAD) sortable-u32 keys, threshold applied, pads=0.
// float4 tile loads; uint4 key stores (thread = 4-prior group x class-slice).
__global__ __launch_bounds__(256) void transpose_keys(const float* __restrict__ conf,
                                                      uint32_t* __restrict__ keys) {
    const int b = blockIdx.x / NCH2;
    const int ch = blockIdx.x % NCH2;
    const int p0 = ch * 256;
    const int n = min(256, P_ - p0);          // 256 or 28; always %4 == 0
    const int tid = threadIdx.x;
    __shared__ float tile[256 * C_];
    const float4* src4 = (const float4*)(conf + ((size_t)b * P_ + p0) * C_);
    float4* tile4 = (float4*)tile;
    const int tot4 = (n * C_) >> 2;
    for (int i = tid; i < tot4; i += 256) tile4[i] = src4[i];
    __syncthreads();
    uint32_t* dst = keys + (size_t)b * C_ * PPAD + p0;
    const int pg = tid & 63;                  // 4-prior group
    const int cs = tid >> 6;                  // class slice 0..3
    const int ng = n >> 2;                    // 64 or 7
    if (pg < ng) {
        for (int c = cs; c < C_; c += 4) {
            const float* tp = &tile[4 * pg * C_ + c];
            uint4 k;
            k.x = keyof(tp[0 * C_]);
            k.y = keyof(tp[1 * C_]);
            k.z = keyof(tp[2 * C_]);
            k.w = keyof(tp[3 * C_]);
            *(uint4*)(dst + (size_t)c * PPAD + 4 * pg) = k;
        }
    }
    if (ch == NCH2 - 1 && pg == ng) {         // single pad group (PPAD-P_ == 4)
        for (int c = cs; c < C_; c += 4)
            *(uint4*)(dst + (size_t)c * PPAD + 4 * pg) = make_uint4(0u, 0u, 0u, 0u);
    }
}

template<bool RAW>
__global__ __launch_bounds__(NT, 6) void detect_kernel(
    const float* __restrict__ loc, const float* __restrict__ prior,
    const uint32_t* __restrict__ keys, const float* __restrict__ conf,
    float* __restrict__ out)
{
    const int task = blockIdx.x;
    const int b = task / C_;
    const int c = task % C_;
    const int tid = threadIdx.x;
    const int lane = tid & 63;
    float* outp = out + (size_t)task * TOPK * 5;

    if (c == 0) {  // out.at[:,0].set(0.0)
        for (int e = tid; e < TOPK * 5; e += NT) outp[e] = 0.0f;
        return;
    }

    __shared__ uint64_t cand[256];
    __shared__ float4 bbox[TOPK];
    __shared__ float bs[TOPK];
    __shared__ unsigned long long msk[TOPK * 4];
    __shared__ unsigned long long vmask[4];
    __shared__ int order[TOPK];
    __shared__ int s_cnt, s_nk;
    __shared__ int s_c2[2];

    // ---- load this task's 8736 keys into registers as uint4 (pads = 0) ----
    uint4 kv[KV4];
    if (!RAW) {
        const uint4* kp = (const uint4*)(keys + (size_t)task * PPAD);
        #pragma unroll
        for (int r = 0; r < KV4; ++r) {
            int q = tid + r * NT;
            kv[r] = (q < PPAD / 4) ? kp[q] : make_uint4(0u, 0u, 0u, 0u);
        }
    } else {
        const float* sp = conf + (size_t)b * P_ * C_ + c;
        #pragma unroll
        for (int r = 0; r < KV4; ++r) {
            uint32_t uu[4];
            #pragma unroll
            for (int c4 = 0; c4 < 4; ++c4) {
                int p = (tid + r * NT) * 4 + c4;
                if (p < P_) {
                    float v = sp[(size_t)p * C_];
                    v = (v > CONF_T) ? v : -1.0f;
                    uu[c4] = f2s(v);
                } else uu[c4] = 0u;
            }
            kv[r] = make_uint4(uu[0], uu[1], uu[2], uu[3]);
        }
    }

    // ---- one-time zeroing (hidden under the in-flight global key loads) ----
    if (tid == 0) s_cnt = 0;
    if (tid < 2) s_c2[tid] = 0;
    for (int i2 = tid; i2 < TOPK * 4; i2 += NT) msk[i2] = 0ull;
    __syncthreads();

    // ---- top-200 threshold via interpolated count-search (conf ~ uniform:
    //      first probe lands count in [200,256] ~94% of the time; regula-falsi
    //      step + bisection fallback guarantees progress) ----
    uint32_t lo = 0u, hi = 0xFFFFFFFFu;
    uint32_t t = f2s(1.0f - (float)TGT / (float)P_);
    uint32_t vthr = 0u;
    for (int it = 0; ; ++it) {
        const int slot = it & 1;
        int my = 0;
        #pragma unroll
        for (int r = 0; r < KV4; ++r)
            my += (kv[r].x >= t) + (kv[r].y >= t) + (kv[r].z >= t) + (kv[r].w >= t);
        #pragma unroll
        for (int d = 1; d < 64; d <<= 1) my += __shfl_down(my, d);
        if (lane == 0) atomicAdd(&s_c2[slot], my);
        __syncthreads();
        const int cnt = s_c2[slot];              // uniform across block
        __syncthreads();
        if (tid == 0) s_c2[slot] = 0;            // reused at it+2; it+1's barriers order this
        if (cnt >= TOPK && cnt <= 256) { vthr = t; break; }
        if (cnt > 256) lo = t; else hi = t;
        if (hi - lo <= 1) { vthr = lo; break; }  // tie collapse: measure-zero on f32 uniforms
        uint32_t tn = 0;
        bool bis = (it >= 8) || (cnt == 0);
        if (!bis) {
            const float sc = s2f(t);
            const float sn = 1.0f - (1.0f - sc) * (float)TGT / (float)cnt;
            tn = f2s(sn);
            if (!(tn > lo && tn < hi)) bis = true;
        }
        if (bis) tn = lo + ((hi - lo) >> 1);
        t = tn;
    }

    // ---- compact candidates >= vthr ----
    #pragma unroll
    for (int r = 0; r < KV4; ++r) {
        const int pb = (tid + r * NT) * 4;
        uint32_t uu[4] = {kv[r].x, kv[r].y, kv[r].z, kv[r].w};
        #pragma unroll
        for (int c4 = 0; c4 < 4; ++c4) {
            uint32_t u = uu[c4];
            if (u >= vthr) {
                int pos = atomicAdd(&s_cnt, 1);
                if (pos < 256) cand[pos] = ((uint64_t)u << 32) | (uint32_t)(~(uint32_t)(pb + c4));
            }
        }
    }
    __syncthreads();
    if (tid < 256 && tid >= s_cnt) cand[tid] = 0ull;   // pad sorts to the end
    __syncthreads();

    // ---- bitonic sort 256 keys desc (val desc, idx asc) == jax.lax.top_k ----
    uint64_t v = (tid < 256) ? cand[tid] : 0ull;
    for (int kk = 2; kk <= 256; kk <<= 1) {
        for (int j = kk >> 1; j > 0; j >>= 1) {
            if (j >= 64) {
                __syncthreads();
                if (tid < 256) cand[tid] = v;
                __syncthreads();
                if (tid < 256) {
                    uint64_t pv = cand[tid ^ j];
                    bool keepmax = (((tid & j) == 0) == ((tid & kk) == 0));
                    v = keepmax ? (v > pv ? v : pv) : (v < pv ? v : pv);
                }
            } else if (tid < 256) {
                uint64_t pv = __shfl_xor(v, j);
                bool keepmax = (((tid & j) == 0) == ((tid & kk) == 0));
                v = keepmax ? (v > pv ? v : pv) : (v < pv ? v : pv);
            }
        }
    }

    // ---- decode top-200 boxes (exact ref f32 op order, no contraction) ----
    float my_sc = -1.0f;
    if (tid < TOPK) {
        uint32_t su = (uint32_t)(v >> 32);
        int p = (int)(~(uint32_t)v);
        my_sc = s2f(su);
        const float4 l4 = *(const float4*)(loc + ((size_t)b * P_ + p) * 4);
        const float4 pr = *(const float4*)(prior + (size_t)p * 4);
        float cx = __fadd_rn(pr.x, __fmul_rn(__fmul_rn(l4.x, 0.1f), pr.z));
        float cy = __fadd_rn(pr.y, __fmul_rn(__fmul_rn(l4.y, 0.1f), pr.w));
        float ew = (float)exp((double)__fmul_rn(l4.z, 0.2f));
        float eh = (float)exp((double)__fmul_rn(l4.w, 0.2f));
        float w  = __fmul_rn(pr.z, ew);
        float h  = __fmul_rn(pr.w, eh);
        float x1 = __fsub_rn(cx, __fmul_rn(w, 0.5f));
        float y1 = __fsub_rn(cy, __fmul_rn(h, 0.5f));
        float x2 = __fadd_rn(x1, w);
        float y2 = __fadd_rn(y1, h);
        bs[tid] = my_sc;
        bbox[tid] = make_float4(x1, y1, x2, y2);
    }
    {
        unsigned long long bm = __ballot(tid < TOPK && my_sc > CONF_T);
        if (lane == 0 && tid < 256) vmask[tid >> 6] = bm;
    }
    __syncthreads();

    // ---- pairwise IoU: balanced row-pairing; areas recomputed inline
    //      (bit-identical ops to ref's precompute; unloads the LDS pipe) ----
    if (tid < 500) {
        const int rp = tid / 5;        // row-pair id in [0,100)
        const int s  = tid - rp * 5;   // sub-lane in [0,5)
        #pragma unroll
        for (int pass = 0; pass < 2; ++pass) {
            const int j  = pass ? (199 - rp) : rp;
            const int i0 = j + 1 + s;
            const float4 bj = bbox[j];
            const float  aj = __fmul_rn(__fsub_rn(bj.z, bj.x), __fsub_rn(bj.w, bj.y));
            for (int i = i0; i < TOPK; i += 5) {
                const float4 bi = bbox[i];
                float xx1 = fmaxf(bj.x, bi.x);
                float yy1 = fmaxf(bj.y, bi.y);
                float xx2 = fminf(bj.z, bi.z);
                float yy2 = fminf(bj.w, bi.w);
                float dx = fmaxf(__fsub_rn(xx2, xx1), 0.0f);
                float dy = fmaxf(__fsub_rn(yy2, yy1), 0.0f);
                float inter = __fmul_rn(dx, dy);
                if (inter > 0.0f) {
                    float ai = __fmul_rn(__fsub_rn(bi.z, bi.x), __fsub_rn(bi.w, bi.y));
                    float uni = __fsub_rn(__fadd_rn(aj, ai), inter);
                    float t45 = __fmul_rn(NMS_T, uni);
                    float mar = __fmul_rn(t45, 1e-6f);
                    bool sup;
                    if (inter > __fadd_rn(t45, mar)) sup = true;
                    else if (inter < __fsub_rn(t45, mar)) sup = false;
                    else sup = (inter / uni > NMS_T);   // exact IEEE path, tie band only
                    if (sup) atomicOr(&msk[j * 4 + (i >> 6)], 1ull << (i & 63));
                }
            }
        }
    }
    __syncthreads();

    // ---- greedy NMS: word-blocked wave-0 scan (1 shfl/pick, deferred cross-word OR) ----
    if (tid < 64) {
        const int L = tid;
        auto or_reduce = [&](unsigned long long x) {
            #pragma unroll
            for (int d = 1; d < 64; d <<= 1) x |= __shfl_xor(x, d);
            return x;
        };
        unsigned long long s1 = 0, s2 = 0, s3 = 0;   // incoming suppression, words 1..3
        int nk = 0;
        #pragma unroll
        for (int w = 0; w < 4; ++w) {
            const int j = (w << 6) | L;
            unsigned long long r0 = 0, r1 = 0, r2 = 0, r3 = 0;
            if (j < TOPK) {
                const unsigned long long* mr = &msk[j * 4];
                r0 = mr[0]; r1 = mr[1]; r2 = mr[2]; r3 = mr[3];
            }
            const unsigned long long rself = (w == 0) ? r0 : (w == 1) ? r1
                                           : (w == 2) ? r2 : r3;
            unsigned long long sw = (w == 0) ? 0ull : (w == 1) ? s1
                                  : (w == 2) ? s2 : s3;
            unsigned long long alive = vmask[w] & ~sw;
            unsigned long long pm = 0;
            while (alive) {
                int jl = __ffsll(alive) - 1;
                if (L == 0) order[nk] = (w << 6) | jl;
                ++nk;
                sw |= __shfl(rself, jl);             // suppression within this word
                pm |= (1ull << jl);
                alive &= ~(sw | (1ull << jl));
            }
            if (pm) {   // deferred: OR picked rows' later-word masks (mask bits are i>j only)
                const bool picked = (pm >> L) & 1ull;
                if (w == 0) {
                    s1 |= or_reduce(picked ? r1 : 0ull);
                    s2 |= or_reduce(picked ? r2 : 0ull);
                    s3 |= or_reduce(picked ? r3 : 0ull);
                } else if (w == 1) {
                    s2 |= or_reduce(picked ? r2 : 0ull);
                    s3 |= or_reduce(picked ? r3 : 0ull);
                } else if (w == 2) {
                    s3 |= or_reduce(picked ? r3 : 0ull);
                }
            }
        }
        if (L == 0) s_nk = nk;
    }
    __syncthreads();

    // ---- compacted output ----
    const int nk = s_nk;
    for (int e = tid; e < TOPK * 5; e += NT) {
        int r = e / 5;
        int f = e - r * 5;
        float val = 0.0f;
        if (r < nk) {
            int j = order[r];
            float4 bb = bbox[j];
            val = (f == 0) ? bs[j] : (f == 1) ? bb.x : (f == 2) ? bb.y
                : (f == 3) ? bb.z : bb.w;
        }
        outp[e] = val;
    }
}

extern "C" void kernel_launch(void* const* d_in, const int* in_sizes, int n_in,
                              void* d_out, int out_size, void* d_ws, size_t ws_size,
                              hipStream_t stream) {
    const float* loc   = (const float*)d_in[0];
    const float* conf  = (const float*)d_in[1];
    const float* prior = (const float*)d_in[2];
    float* out = (float*)d_out;

    const size_t need = (size_t)B_ * C_ * PPAD * sizeof(uint32_t);
    if (ws_size >= need) {
        uint32_t* keys = (uint32_t*)d_ws;
        transpose_keys<<<B_ * NCH2, 256, 0, stream>>>(conf, keys);
        detect_kernel<false><<<B_ * C_, NT, 0, stream>>>(loc, prior, keys, conf, out);
    } else {
        detect_kernel<true><<<B_ * C_, NT, 0, stream>>>(loc, prior, nullptr, conf, out);
    }
}